// Round 4
// baseline (249.101 us; speedup 1.0000x reference)
//
#include <hip/hip_runtime.h>
#include <hip/hip_bf16.h>

typedef __bf16 bf16_t;
typedef __bf16 bf16x8 __attribute__((ext_vector_type(8)));
typedef __bf16 bf16x4 __attribute__((ext_vector_type(4)));
typedef float f32x4 __attribute__((ext_vector_type(4)));

#define NB 8
#define NS 4096
#define NH 256
#define NF 512
#define NE 16
#define NTOK (NB*NS)          // 32768
#define TT 64                 // tokens per tile
#define NCH 16                // f-chunks of 32
#define HS_STRIDE 40          // 32 + 8 pad (80B = 5*16: rows 16B-aligned)

// async global->LDS, 16B per lane, linear LDS dest (wave-uniform base + lane*16)
__device__ __forceinline__ void load_lds16(const void* g, void* l) {
    __builtin_amdgcn_global_load_lds(
        (const __attribute__((address_space(1))) unsigned int*)g,
        (__attribute__((address_space(3))) unsigned int*)l, 16, 0, 0);
}

// ---------------------------------------------------------------------------
// Kernel 1: transpose+convert weights (fp32 in, bf16 out), vectorized stores.
// w1 [E][H][F] -> w1t [E][F][H]  with XOR bank-swizzle baked into the k index:
//   element (f,k) stored at f*256 + ((k>>3)^(f&7))*8 + (k&7)
// w2 [E][F][H] -> w2t [E][F/32][H][32] chunked:
//   element (f,h) stored at (f>>5)*8192 + h*32 + (f&31)
// ---------------------------------------------------------------------------
__global__ __launch_bounds__(256) void transpose_kernel(
    const float* __restrict__ w1, const float* __restrict__ w2,
    bf16_t* __restrict__ w1t, bf16_t* __restrict__ w2t)
{
    __shared__ float tile[32][33];
    int bid = blockIdx.x;
    const float* src; bf16_t* dst; int R, C; int isw1;
    if (bid < 2048) { src = w1; dst = w1t; R = NH; C = NF; isw1 = 1; }
    else            { bid -= 2048; src = w2; dst = w2t; R = NF; C = NH; isw1 = 0; }
    int e = bid >> 7;
    int t = bid & 127;
    int tcols = C / 32;
    int tr = (t / tcols) * 32, tc = (t % tcols) * 32;
    src += (size_t)e * R * C;
    dst += (size_t)e * R * C;
    int tx = threadIdx.x & 31, ty0 = threadIdx.x >> 5;
    #pragma unroll
    for (int i = 0; i < 4; i++) {
        int ty = ty0 + i * 8;
        tile[ty][tx] = src[(size_t)(tr + ty) * C + tc + tx];
    }
    __syncthreads();
    if (threadIdx.x < 128) {
        int j = threadIdx.x & 31;   // output-row local index
        int g = threadIdx.x >> 5;   // which group of 8 output-cols
        bf16x8 v;
        #pragma unroll
        for (int jj = 0; jj < 8; jj++)
            v[jj] = (bf16_t)tile[g * 8 + jj][j];
        size_t idx;
        if (isw1) {
            int f  = tc + j;          // output row
            int kb = tr + g * 8;      // 8 consecutive k, kb%8==0
            idx = (size_t)f * NH + ((((kb >> 3) ^ (f & 7))) << 3);
        } else {
            int h  = tc + j;          // output row within chunk
            int fb = tr + g * 8;      // 8 consecutive f, fb%8==0, same 32-chunk
            idx = ((size_t)(fb >> 5) * NH + h) * 32 + (fb & 31);
        }
        *(bf16x8*)(dst + idx) = v;
    }
}

// ---------------------------------------------------------------------------
// Kernel 2: gating, v2. No LDS for gate_w: the inner reads are wave-uniform,
// so direct global reads scalarize to s_load (K$/SMEM pipe) instead of the
// previous 4096 ds_read_b32 broadcasts per wave on the LDS pipe.
// ---------------------------------------------------------------------------
__global__ __launch_bounds__(256) void gate_kernel(
    const float* __restrict__ x, const float* __restrict__ gate_w,
    const float* __restrict__ gate_b,
    int* __restrict__ counts, int* __restrict__ bucket_enc,
    float* __restrict__ bucket_gw, bf16_t* __restrict__ xb)
{
    __shared__ int lcnt[NE];
    __shared__ int gbase[NE];
    if (threadIdx.x < NE) lcnt[threadIdx.x] = 0;
    __syncthreads();

    int tok = blockIdx.x * 256 + threadIdx.x;
    const float4* xr = (const float4*)(x + (size_t)tok * NH);
    bf16x4* xbr = (bf16x4*)(xb + (size_t)tok * NH);
    float acc[NE];
    #pragma unroll
    for (int e = 0; e < NE; e++) acc[e] = gate_b[e];
    for (int h4 = 0; h4 < NH / 4; h4++) {
        float4 xv = xr[h4];
        bf16x4 xo;
        xo[0] = (bf16_t)xv.x; xo[1] = (bf16_t)xv.y;
        xo[2] = (bf16_t)xv.z; xo[3] = (bf16_t)xv.w;
        xbr[h4] = xo;
        #pragma unroll
        for (int j = 0; j < 4; j++) {
            float xs = (j == 0) ? xv.x : (j == 1) ? xv.y : (j == 2) ? xv.z : xv.w;
            const float* wr = gate_w + (h4 * 4 + j) * NE;   // uniform addr -> s_load
            #pragma unroll
            for (int e = 0; e < NE; e++) acc[e] += xs * wr[e];
        }
    }
    // top-2 (jax.lax.top_k order: strict >, earlier index wins ties)
    float v0 = -1e30f, v1 = -1e30f; int i0 = 0, i1 = 0;
    #pragma unroll
    for (int e = 0; e < NE; e++) {
        float a = acc[e];
        if (a > v0)      { v1 = v0; i1 = i0; v0 = a; i0 = e; }
        else if (a > v1) { v1 = a; i1 = e; }
    }
    float e1 = __expf(v1 - v0);
    float s  = 1.f + e1;
    int   pe[2] = { i0, i1 };
    float pg[2] = { 1.f / s, e1 / s };
    int   po[2];
    po[0] = atomicAdd(&lcnt[i0], 1);
    po[1] = atomicAdd(&lcnt[i1], 1);
    __syncthreads();
    if (threadIdx.x < NE)
        gbase[threadIdx.x] = atomicAdd(&counts[threadIdx.x], lcnt[threadIdx.x]);
    __syncthreads();
    #pragma unroll
    for (int k = 0; k < 2; k++) {
        int e = pe[k];
        int pos = gbase[e] + po[k];
        bucket_enc[e * NTOK + pos] = tok | (k << 20);
        bucket_gw [e * NTOK + pos] = pg[k];
    }
}

// ---------------------------------------------------------------------------
// Kernel 3: fused expert FFN, v6.
//  - v5 structure (operand swap, X in regs, w1 via global_load_lds dbuf)
//  - epilogue stages output tile in W1s4 (dead after last GEMM1; exactly
//    32 KB = 64 x 512 B) -> full-line uint4 stores, kills the RMW
//    write/fetch amplification (WRITE 63->34 MB, FETCH 42->25 MB)
//  - w2 A-frags double-buffered in registers (L2 latency hidden)
//  - grid 1024 (64 blocks/expert ~= 1 tile/block, load-balanced)
// ---------------------------------------------------------------------------
__global__ __launch_bounds__(256, 3) void moe_kernel(
    const bf16_t* __restrict__ xb,
    const bf16_t* __restrict__ w1t,  // [E][F][H] bf16, k-swizzled
    const float*  __restrict__ b1,
    const bf16_t* __restrict__ w2t,  // [E][F/32][H][32] bf16 chunked
    const float*  __restrict__ b2,
    const int* __restrict__ counts,
    const int* __restrict__ bucket_enc,
    const float* __restrict__ bucket_gw,
    bf16_t* __restrict__ pairbuf)    // [NTOK*2][NH] bf16
{
    __shared__ uint4 W1s4[2][1024];                        // 32 KB (2x16KB)
    __shared__ __align__(16) bf16_t Hs[2][TT][HS_STRIDE];  // 10240 B
    __shared__ int   tok_s[TT];
    __shared__ float gw_s[TT];
    // ~43.5 KB -> 3 blocks/CU (12 waves/CU)

    int flat = blockIdx.x;               // 1024 blocks
    int e    = (flat & 7) * 2 + ((flat >> 3) & 1);  // 2 experts per XCD
    int tile0 = flat >> 4;               // 0..63, stride 64
    int n_e = counts[e];
    int wave = threadIdx.x >> 6;
    int lane = threadIdx.x & 63;
    int l15 = lane & 15, q = lane >> 4;

    const bf16_t* w1te = w1t + (size_t)e * NF * NH;
    const bf16_t* w2te = w2t + (size_t)e * NF * NH;

    int ntiles = (n_e + TT - 1) / TT;
    for (int tile = tile0; tile < ntiles; tile += 64) {
        int tstart = tile * TT;
        __syncthreads();   // protect tok_s/gw_s + LDS reuse across tiles
        if (threadIdx.x < TT) {
            int slot = tstart + threadIdx.x;
            if (slot < n_e) {
                tok_s[threadIdx.x] = bucket_enc[e * NTOK + slot];
                gw_s [threadIdx.x] = bucket_gw [e * NTOK + slot];
            } else { tok_s[threadIdx.x] = 0; gw_s[threadIdx.x] = 0.f; }
        }
        __syncthreads();

        // issue w1 chunk 0 -> W1s[0] (async DMA)
        {
            const uint4* gw1 = (const uint4*)w1te;
            #pragma unroll
            for (int i = 0; i < 4; i++)
                load_lds16(gw1 + i * 256 + threadIdx.x, &W1s4[0][i * 256 + threadIdx.x]);
        }
        // load this wave's 16 X rows into registers (B-frags for GEMM1)
        int mytok = tok_s[wave * 16 + l15] & 0xFFFFF;
        const uint4* xrow = (const uint4*)(xb + (size_t)mytok * NH);
        uint4 xf[8];
        #pragma unroll
        for (int ks = 0; ks < 8; ks++) xf[ks] = xrow[ks * 4 + q];
        // w2 A-frags for chunk 0 (register double-buffer)
        bf16x8 bf2c[4], bf2n[4];
        #pragma unroll
        for (int nt = 0; nt < 4; nt++) {
            int hh = wave * 64 + nt * 16 + l15;
            bf2c[nt] = *(const bf16x8*)&w2te[((size_t)hh << 5) + q * 8];
        }
        __syncthreads();   // drains gll: W1s[0] ready

        f32x4 oacc[4][4];
        #pragma unroll
        for (int a = 0; a < 4; a++)
            #pragma unroll
            for (int b = 0; b < 4; b++) { f32x4 z = {0.f,0.f,0.f,0.f}; oacc[a][b] = z; }

        for (int ch = 0; ch < NCH; ch++) {
            int buf = ch & 1;
            bool have_next = (ch + 1 < NCH);
            // -- async prefetch w1 chunk ch+1 -> W1s[buf^1]
            if (have_next) {
                const uint4* gw1 = (const uint4*)w1te + (size_t)(ch + 1) * 1024;
                #pragma unroll
                for (int i = 0; i < 4; i++)
                    load_lds16(gw1 + i * 256 + threadIdx.x,
                               &W1s4[buf ^ 1][i * 256 + threadIdx.x]);
                // -- prefetch w2 A-frags for chunk ch+1 (used after NEXT barrier)
                #pragma unroll
                for (int nt = 0; nt < 4; nt++) {
                    int hh = wave * 64 + nt * 16 + l15;
                    bf2n[nt] = *(const bf16x8*)&w2te[(((size_t)(ch + 1) * NH + hh) << 5) + q * 8];
                }
            }
            // ---- GEMM1: A = w1 (rows=f from LDS), B = X (cols=tokens, regs)
            f32x4 hacc[2]; { f32x4 z = {0.f,0.f,0.f,0.f}; hacc[0] = z; hacc[1] = z; }
            const bf16_t* w1s = (const bf16_t*)W1s4[buf];
            #pragma unroll
            for (int ks = 0; ks < 8; ks++) {
                bf16x8 xfrag = *(const bf16x8*)&xf[ks];
                #pragma unroll
                for (int n = 0; n < 2; n++) {
                    int fl = n * 16 + l15;
                    bf16x8 wf = *(const bf16x8*)&w1s[fl * NH + ((((ks * 4 + q) ^ (fl & 7))) << 3)];
                    hacc[n] = __builtin_amdgcn_mfma_f32_16x16x32_bf16(wf, xfrag, hacc[n], 0, 0, 0);
                }
            }
            // bias + relu -> Hs[buf]; lane owns 4 consecutive f -> 8B stores
            #pragma unroll
            for (int n = 0; n < 2; n++) {
                int f0 = ch * 32 + n * 16 + q * 4;
                float4 b1v = *(const float4*)&b1[e * NF + f0];
                bf16x4 hv;
                #pragma unroll
                for (int r = 0; r < 4; r++) {
                    float v = hacc[n][r] + ((const float*)&b1v)[r];
                    v = v > 0.f ? v : 0.f;
                    hv[r] = (bf16_t)v;
                }
                *(bf16x4*)&Hs[buf][wave * 16 + l15][n * 16 + q * 4] = hv;
            }
            __syncthreads();   // Hs[buf] complete; also drains w1 prefetch
            // ---- GEMM2: A = w2 (rows=h-cols, regs), B = H (cols=tokens, LDS)
            #pragma unroll
            for (int mt = 0; mt < 4; mt++) {
                bf16x8 hf = *(const bf16x8*)&Hs[buf][mt * 16 + l15][q * 8];
                #pragma unroll
                for (int nt = 0; nt < 4; nt++) {
                    oacc[mt][nt] = __builtin_amdgcn_mfma_f32_16x16x32_bf16(bf2c[nt], hf, oacc[mt][nt], 0, 0, 0);
                }
            }
            if (have_next) {
                #pragma unroll
                for (int nt = 0; nt < 4; nt++) bf2c[nt] = bf2n[nt];
            }
        }
        // ---- epilogue: +b2, *gate_w -> stage tile (bf16, swizzled) in the
        //      now-dead W1s4 (last read was GEMM1 ch15, before its barrier),
        //      then flush full 512-B rows as uint4 (no partial-line writes).
        {
            bf16_t* stage = (bf16_t*)W1s4;   // 64 rows x 512 B
            float4 b2v[4];
            #pragma unroll
            for (int nt = 0; nt < 4; nt++)
                b2v[nt] = *(const float4*)&b2[e * NH + wave * 64 + nt * 16 + q * 4];
            #pragma unroll
            for (int mt = 0; mt < 4; mt++) {
                int row = mt * 16 + l15;
                float gw = gw_s[row];
                #pragma unroll
                for (int nt = 0; nt < 4; nt++) {
                    // byte pos in row: wave*128 + nt*32 + q*8 -> 16B unit + half
                    int unit = wave * 8 + nt * 2 + (q >> 1);
                    int su = unit ^ (row & 7);          // bank swizzle
                    bf16x4 ov;
                    #pragma unroll
                    for (int r = 0; r < 4; r++)
                        ov[r] = (bf16_t)((oacc[mt][nt][r] + ((const float*)&b2v[nt])[r]) * gw);
                    *(bf16x4*)&stage[row * NH + su * 8 + (q & 1) * 4] = ov;
                }
            }
        }
        __syncthreads();
        {
            const uint4* stage4 = &W1s4[0][0];
            int nrows = n_e - tstart; if (nrows > TT) nrows = TT;
            int c  = threadIdx.x & 31;
            int r0 = threadIdx.x >> 5;
            #pragma unroll
            for (int i = 0; i < 8; i++) {
                int r = r0 + i * 8;
                if (r < nrows) {
                    int enc = tok_s[r];
                    int tok = enc & 0xFFFFF;
                    int k   = enc >> 20;
                    ((uint4*)(pairbuf + ((size_t)(tok * 2 + k)) * NH))[c] =
                        stage4[r * 32 + (c ^ (r & 7))];
                }
            }
        }
    }
}

// ---------------------------------------------------------------------------
// Kernel 4: residual + LayerNorm, vectorized. Wave-per-token (64 lanes x 4 h),
// float4/bf16x4 loads, shfl_xor reduce, no LDS, no syncthreads.
// ---------------------------------------------------------------------------
__global__ __launch_bounds__(256) void ln_kernel(
    const float* __restrict__ x, const bf16_t* __restrict__ pairbuf,
    const float* __restrict__ gamma, const float* __restrict__ beta,
    float* __restrict__ out)
{
    int tok  = blockIdx.x * 4 + (threadIdx.x >> 6);
    int lane = threadIdx.x & 63;
    float4 xv = *(const float4*)(x + (size_t)tok * NH + lane * 4);
    bf16x4 p0 = *(const bf16x4*)(pairbuf + (size_t)(tok * 2)     * NH + lane * 4);
    bf16x4 p1 = *(const bf16x4*)(pairbuf + (size_t)(tok * 2 + 1) * NH + lane * 4);
    float y0 = xv.x + (float)p0[0] + (float)p1[0];
    float y1 = xv.y + (float)p0[1] + (float)p1[1];
    float y2 = xv.z + (float)p0[2] + (float)p1[2];
    float y3 = xv.w + (float)p0[3] + (float)p1[3];
    float s  = y0 + y1 + y2 + y3;
    float s2 = y0 * y0 + y1 * y1 + y2 * y2 + y3 * y3;
    #pragma unroll
    for (int o = 32; o > 0; o >>= 1) {
        s  += __shfl_xor(s, o);
        s2 += __shfl_xor(s2, o);
    }
    float mu   = s * (1.f / NH);
    float var  = s2 * (1.f / NH) - mu * mu;
    float rstd = rsqrtf(var + 1e-5f);
    float4 gv = *(const float4*)(gamma + lane * 4);
    float4 bv = *(const float4*)(beta  + lane * 4);
    float4 o4;
    o4.x = (y0 - mu) * rstd * gv.x + bv.x;
    o4.y = (y1 - mu) * rstd * gv.y + bv.y;
    o4.z = (y2 - mu) * rstd * gv.z + bv.z;
    o4.w = (y3 - mu) * rstd * gv.w + bv.w;
    *(float4*)(out + (size_t)tok * NH + lane * 4) = o4;
}

// ---------------------------------------------------------------------------
extern "C" void kernel_launch(void* const* d_in, const int* in_sizes, int n_in,
                              void* d_out, int out_size, void* d_ws, size_t ws_size,
                              hipStream_t stream) {
    const float* x      = (const float*)d_in[0];
    const float* gate_w = (const float*)d_in[1];
    const float* gate_b = (const float*)d_in[2];
    const float* w1     = (const float*)d_in[3];
    const float* b1     = (const float*)d_in[4];
    const float* w2     = (const float*)d_in[5];
    const float* b2     = (const float*)d_in[6];
    const float* gamma  = (const float*)d_in[7];
    const float* beta   = (const float*)d_in[8];
    float* out = (float*)d_out;

    char* ws = (char*)d_ws;
    const size_t MB = 1024 * 1024;
    int*    counts     = (int*)ws;                       // 256 B
    int*    bucket_enc = (int*)(ws + 256);               // 2 MB
    float*  bucket_gw  = (float*)(ws + 256 + 2 * MB);    // 2 MB
    bf16_t* w1t        = (bf16_t*)(ws + 256 + 4 * MB);   // 4 MB
    bf16_t* w2t        = (bf16_t*)(ws + 256 + 8 * MB);   // 4 MB
    bf16_t* xb         = (bf16_t*)(ws + 256 + 12 * MB);  // 16 MB
    bf16_t* pairbuf    = (bf16_t*)(ws + 256 + 28 * MB);  // 32 MB

    hipMemsetAsync(counts, 0, 256, stream);
    transpose_kernel<<<4096, 256, 0, stream>>>(w1, w2, w1t, w2t);
    gate_kernel<<<128, 256, 0, stream>>>(x, gate_w, gate_b, counts, bucket_enc, bucket_gw, xb);
    moe_kernel<<<1024, 256, 0, stream>>>(xb, w1t, b1, w2t, b2, counts, bucket_enc, bucket_gw, pairbuf);
    ln_kernel<<<NTOK / 4, 256, 0, stream>>>(x, pairbuf, gamma, beta, out);
}

// Round 5
// 233.174 us; speedup vs baseline: 1.0683x; 1.0683x over previous
//
#include <hip/hip_runtime.h>
#include <hip/hip_bf16.h>

typedef __bf16 bf16_t;
typedef __bf16 bf16x8 __attribute__((ext_vector_type(8)));
typedef __bf16 bf16x4 __attribute__((ext_vector_type(4)));
typedef float f32x4 __attribute__((ext_vector_type(4)));

#define NB 8
#define NS 4096
#define NH 256
#define NF 512
#define NE 16
#define NTOK (NB*NS)          // 32768
#define TT 64                 // tokens per tile
#define NCH 16                // f-chunks of 32
#define HS_STRIDE 40          // 32 + 8 pad (80B = 5*16: rows 16B-aligned)

// async global->LDS, 16B per lane, linear LDS dest (wave-uniform base + lane*16)
__device__ __forceinline__ void load_lds16(const void* g, void* l) {
    __builtin_amdgcn_global_load_lds(
        (const __attribute__((address_space(1))) unsigned int*)g,
        (__attribute__((address_space(3))) unsigned int*)l, 16, 0, 0);
}

// ---------------------------------------------------------------------------
// Kernel 1 (fused prep): gate blocks [0,128) + transpose blocks [128,4224).
// Gate blocks are dispatched FIRST so their long per-token loop overlaps the
// 4096 short transpose blocks -> no more half-GPU-idle gate phase, one less
// launch gap.
//
// transpose: w1 [E][H][F] -> w1t [E][F][H] bf16, k-index XOR bank-swizzled:
//   element (f,k) at f*256 + ((k>>3)^(f&7))*8 + (k&7)
// w2 [E][F][H] -> w2t [E][F/32][H][32] bf16 chunked (per-chunk contiguous 16KB)
// gate: fp32 logits, top-2, softmax(2), hierarchical scatter + x->bf16 (xb)
// ---------------------------------------------------------------------------
__global__ __launch_bounds__(256) void prep_kernel(
    const float* __restrict__ w1, const float* __restrict__ w2,
    bf16_t* __restrict__ w1t, bf16_t* __restrict__ w2t,
    const float* __restrict__ x, const float* __restrict__ gate_w,
    const float* __restrict__ gate_b,
    int* __restrict__ counts, int* __restrict__ bucket_enc,
    float* __restrict__ bucket_gw, bf16_t* __restrict__ xb)
{
    __shared__ float tile[32][33];
    __shared__ int lcnt[NE];
    __shared__ int gbase[NE];

    if (blockIdx.x < 128) {
        // ---------------- gate body ----------------
        if (threadIdx.x < NE) lcnt[threadIdx.x] = 0;
        __syncthreads();

        int tok = blockIdx.x * 256 + threadIdx.x;
        const float4* xr = (const float4*)(x + (size_t)tok * NH);
        bf16x4* xbr = (bf16x4*)(xb + (size_t)tok * NH);
        float acc[NE];
        #pragma unroll
        for (int e = 0; e < NE; e++) acc[e] = gate_b[e];
        for (int h4 = 0; h4 < NH / 4; h4++) {
            float4 xv = xr[h4];
            bf16x4 xo;
            xo[0] = (bf16_t)xv.x; xo[1] = (bf16_t)xv.y;
            xo[2] = (bf16_t)xv.z; xo[3] = (bf16_t)xv.w;
            xbr[h4] = xo;
            #pragma unroll
            for (int j = 0; j < 4; j++) {
                float xs = (j == 0) ? xv.x : (j == 1) ? xv.y : (j == 2) ? xv.z : xv.w;
                const float* wr = gate_w + (h4 * 4 + j) * NE;  // uniform -> s_load
                #pragma unroll
                for (int e = 0; e < NE; e++) acc[e] += xs * wr[e];
            }
        }
        // top-2 (jax.lax.top_k order: strict >, earlier index wins ties)
        float v0 = -1e30f, v1 = -1e30f; int i0 = 0, i1 = 0;
        #pragma unroll
        for (int e = 0; e < NE; e++) {
            float a = acc[e];
            if (a > v0)      { v1 = v0; i1 = i0; v0 = a; i0 = e; }
            else if (a > v1) { v1 = a; i1 = e; }
        }
        float e1 = __expf(v1 - v0);
        float s  = 1.f + e1;
        int   pe[2] = { i0, i1 };
        float pg[2] = { 1.f / s, e1 / s };
        int   po[2];
        po[0] = atomicAdd(&lcnt[i0], 1);
        po[1] = atomicAdd(&lcnt[i1], 1);
        __syncthreads();
        if (threadIdx.x < NE)
            gbase[threadIdx.x] = atomicAdd(&counts[threadIdx.x], lcnt[threadIdx.x]);
        __syncthreads();
        #pragma unroll
        for (int k = 0; k < 2; k++) {
            int e = pe[k];
            int pos = gbase[e] + po[k];
            bucket_enc[e * NTOK + pos] = tok | (k << 20);
            bucket_gw [e * NTOK + pos] = pg[k];
        }
        return;
    }

    // ---------------- transpose body ----------------
    int bid = blockIdx.x - 128;
    const float* src; bf16_t* dst; int R, C; int isw1;
    if (bid < 2048) { src = w1; dst = w1t; R = NH; C = NF; isw1 = 1; }
    else            { bid -= 2048; src = w2; dst = w2t; R = NF; C = NH; isw1 = 0; }
    int e = bid >> 7;
    int t = bid & 127;
    int tcols = C / 32;
    int tr = (t / tcols) * 32, tc = (t % tcols) * 32;
    src += (size_t)e * R * C;
    dst += (size_t)e * R * C;
    int tx = threadIdx.x & 31, ty0 = threadIdx.x >> 5;
    #pragma unroll
    for (int i = 0; i < 4; i++) {
        int ty = ty0 + i * 8;
        tile[ty][tx] = src[(size_t)(tr + ty) * C + tc + tx];
    }
    __syncthreads();
    if (threadIdx.x < 128) {
        int j = threadIdx.x & 31;   // output-row local index
        int g = threadIdx.x >> 5;   // which group of 8 output-cols
        bf16x8 v;
        #pragma unroll
        for (int jj = 0; jj < 8; jj++)
            v[jj] = (bf16_t)tile[g * 8 + jj][j];
        size_t idx;
        if (isw1) {
            int f  = tc + j;          // output row
            int kb = tr + g * 8;      // 8 consecutive k, kb%8==0
            idx = (size_t)f * NH + ((((kb >> 3) ^ (f & 7))) << 3);
        } else {
            int h  = tc + j;          // output row within chunk
            int fb = tr + g * 8;      // 8 consecutive f, same 32-chunk
            idx = ((size_t)(fb >> 5) * NH + h) * 32 + (fb & 31);
        }
        *(bf16x8*)(dst + idx) = v;
    }
}

// ---------------------------------------------------------------------------
// Kernel 2: fused expert FFN, v7 = v5 (proven 93 us) + counted-vmcnt barriers.
//  - v5 base: 768 blocks, X in regs, w1 DMA double-buffer, direct bf16x4
//    epilogue stores, chunked w2t.
//  - NEW: per-chunk __syncthreads (which drained vmcnt(0) = full memory
//    latency exposed 16x/tile) replaced by raw s_barrier + counted waits:
//      [B] s_waitcnt vmcnt(12) (last chunk: 4) -> current w1 chunk's DMA done,
//          next chunk's DMA + w2 prefetch stay IN FLIGHT across the barrier
//      [D] s_waitcnt lgkmcnt(0) only (Hs LDS handoff; no vmem drain)
//    b1/b2 moved to LDS so no stray vmem ops pollute the vmcnt FIFO
//    accounting. Queue at [B]: DMA(cur)x4 | bf2n x4, DMA(next)x4, bf2n x4
//    => exactly 12 younger ops. Per-wave wait-then-barrier makes cross-wave
//    DMA visibility sound (each wave's own share done before barrier release).
//  - w2 A-frags register-double-buffered (compiler emits vmcnt(8) before
//    GEMM2, non-draining).
// ---------------------------------------------------------------------------
__global__ __launch_bounds__(256, 3) void moe_kernel(
    const bf16_t* __restrict__ xb,
    const bf16_t* __restrict__ w1t,  // [E][F][H] bf16, k-swizzled
    const float*  __restrict__ b1,
    const bf16_t* __restrict__ w2t,  // [E][F/32][H][32] bf16 chunked
    const float*  __restrict__ b2,
    const int* __restrict__ counts,
    const int* __restrict__ bucket_enc,
    const float* __restrict__ bucket_gw,
    bf16_t* __restrict__ pairbuf)    // [NTOK*2][NH] bf16
{
    __shared__ uint4 W1s4[2][1024];                        // 32 KB (2x16KB)
    __shared__ __align__(16) bf16_t Hs[2][TT][HS_STRIDE];  // 10240 B
    __shared__ int   tok_s[TT];
    __shared__ float gw_s[TT];
    __shared__ float b1_s[NF];                             // 2 KB
    __shared__ float b2_s[NH];                             // 1 KB
    // ~46.5 KB -> 3 blocks/CU (12 waves/CU)

    int flat = blockIdx.x;               // 768 blocks = 3 * 256 CUs
    int xcd  = flat & 7;
    int j    = flat >> 3;                // 0..95
    int e    = xcd * 2 + (j & 1);        // 2 experts per XCD (L2 locality)
    int tile0 = j >> 1;                  // 0..47, stride 48
    int n_e = counts[e];
    int wave = threadIdx.x >> 6;
    int lane = threadIdx.x & 63;
    int l15 = lane & 15, q = lane >> 4;

    const bf16_t* w1te = w1t + (size_t)e * NF * NH;
    const bf16_t* w2te = w2t + (size_t)e * NF * NH;

    // per-expert biases -> LDS once (keeps the K-loop free of stray vmem ops)
    if (threadIdx.x < 256) {
        b1_s[threadIdx.x]       = b1[e * NF + threadIdx.x];
        b1_s[threadIdx.x + 256] = b1[e * NF + threadIdx.x + 256];
        b2_s[threadIdx.x]       = b2[e * NH + threadIdx.x];
    }

    int ntiles = (n_e + TT - 1) / TT;
    for (int tile = tile0; tile < ntiles; tile += 48) {
        int tstart = tile * TT;
        __syncthreads();   // protect tok_s/gw_s + LDS reuse; covers b1_s/b2_s
        if (threadIdx.x < TT) {
            int slot = tstart + threadIdx.x;
            if (slot < n_e) {
                tok_s[threadIdx.x] = bucket_enc[e * NTOK + slot];
                gw_s [threadIdx.x] = bucket_gw [e * NTOK + slot];
            } else { tok_s[threadIdx.x] = 0; gw_s[threadIdx.x] = 0.f; }
        }
        __syncthreads();

        // issue w1 chunk 0 -> W1s[0] (async DMA)
        {
            const uint4* gw1 = (const uint4*)w1te;
            #pragma unroll
            for (int i = 0; i < 4; i++)
                load_lds16(gw1 + i * 256 + threadIdx.x, &W1s4[0][i * 256 + threadIdx.x]);
        }
        // this wave's 16 X rows into registers (B-frags for GEMM1)
        int mytok = tok_s[wave * 16 + l15] & 0xFFFFF;
        const uint4* xrow = (const uint4*)(xb + (size_t)mytok * NH);
        uint4 xf[8];
        #pragma unroll
        for (int ks = 0; ks < 8; ks++) xf[ks] = xrow[ks * 4 + q];
        // w2 A-frags for chunk 0 (register double-buffer)
        bf16x8 bf2c[4], bf2n[4];
        #pragma unroll
        for (int nt = 0; nt < 4; nt++) {
            int hh = wave * 64 + nt * 16 + l15;
            bf2c[nt] = *(const bf16x8*)&w2te[((size_t)hh << 5) + q * 8];
        }
        __syncthreads();   // full drain once per tile: W1s[0]+xf+bf2c ready

        f32x4 oacc[4][4];
        #pragma unroll
        for (int a = 0; a < 4; a++)
            #pragma unroll
            for (int b = 0; b < 4; b++) { f32x4 z = {0.f,0.f,0.f,0.f}; oacc[a][b] = z; }

        for (int ch = 0; ch < NCH; ch++) {
            int buf = ch & 1;
            // -- [A] async prefetch: w1 chunk ch+1 -> W1s[buf^1], w2 ch+1 -> bf2n
            if (ch + 1 < NCH) {
                const uint4* gw1 = (const uint4*)w1te + (size_t)(ch + 1) * 1024;
                #pragma unroll
                for (int i = 0; i < 4; i++)
                    load_lds16(gw1 + i * 256 + threadIdx.x,
                               &W1s4[buf ^ 1][i * 256 + threadIdx.x]);
                #pragma unroll
                for (int nt = 0; nt < 4; nt++) {
                    int hh = wave * 64 + nt * 16 + l15;
                    bf2n[nt] = *(const bf16x8*)&w2te[(((size_t)(ch + 1) * NH + hh) << 5) + q * 8];
                }
                // -- [B] current chunk's DMA done; 12 younger ops stay in flight
                asm volatile("s_waitcnt vmcnt(12)" ::: "memory");
            } else {
                // last chunk: only bf2n(prev)x4 younger than the needed DMA
                asm volatile("s_waitcnt vmcnt(4)" ::: "memory");
            }
            __builtin_amdgcn_s_barrier();
            __builtin_amdgcn_sched_barrier(0);

            // ---- [C] GEMM1: A = w1 (rows=f from LDS), B = X (tokens, regs)
            f32x4 hacc[2]; { f32x4 z = {0.f,0.f,0.f,0.f}; hacc[0] = z; hacc[1] = z; }
            const bf16_t* w1s = (const bf16_t*)W1s4[buf];
            #pragma unroll
            for (int ks = 0; ks < 8; ks++) {
                bf16x8 xfrag = *(const bf16x8*)&xf[ks];
                #pragma unroll
                for (int n = 0; n < 2; n++) {
                    int fl = n * 16 + l15;
                    bf16x8 wf = *(const bf16x8*)&w1s[fl * NH + ((((ks * 4 + q) ^ (fl & 7))) << 3)];
                    hacc[n] = __builtin_amdgcn_mfma_f32_16x16x32_bf16(wf, xfrag, hacc[n], 0, 0, 0);
                }
            }
            // bias(LDS) + relu -> Hs[buf]; lane owns 4 consecutive f -> 8B store
            #pragma unroll
            for (int n = 0; n < 2; n++) {
                int f0 = ch * 32 + n * 16 + q * 4;
                float4 b1v = *(const float4*)&b1_s[f0];
                bf16x4 hv;
                #pragma unroll
                for (int r = 0; r < 4; r++) {
                    float v = hacc[n][r] + ((const float*)&b1v)[r];
                    v = v > 0.f ? v : 0.f;
                    hv[r] = (bf16_t)v;
                }
                *(bf16x4*)&Hs[buf][wave * 16 + l15][n * 16 + q * 4] = hv;
            }
            // -- [D] Hs handoff: LDS-only wait, vmem prefetches stay in flight
            asm volatile("s_waitcnt lgkmcnt(0)" ::: "memory");
            __builtin_amdgcn_s_barrier();
            __builtin_amdgcn_sched_barrier(0);

            // ---- [E] GEMM2: A = w2 (h-cols, regs), B = H (tokens, LDS)
            #pragma unroll
            for (int mt = 0; mt < 4; mt++) {
                bf16x8 hf = *(const bf16x8*)&Hs[buf][mt * 16 + l15][q * 8];
                #pragma unroll
                for (int nt = 0; nt < 4; nt++) {
                    oacc[mt][nt] = __builtin_amdgcn_mfma_f32_16x16x32_bf16(bf2c[nt], hf, oacc[mt][nt], 0, 0, 0);
                }
            }
            if (ch + 1 < NCH) {
                #pragma unroll
                for (int nt = 0; nt < 4; nt++) bf2c[nt] = bf2n[nt];
            }
        }
        // ---- epilogue (v5 direct form): lane holds 4 consecutive h-cols per
        //      (mt,nt) for ONE token -> +b2(LDS), *gate_w, single 8B store.
        int nrows = n_e - tstart; if (nrows > TT) nrows = TT;
        float4 b2v[4];
        #pragma unroll
        for (int nt = 0; nt < 4; nt++)
            b2v[nt] = *(const float4*)&b2_s[wave * 64 + nt * 16 + q * 4];
        #pragma unroll
        for (int mt = 0; mt < 4; mt++) {
            int trow = mt * 16 + l15;
            int enc  = tok_s[trow];
            float gw = gw_s[trow];
            bool valid = trow < nrows;
            int tok = enc & 0xFFFFF;
            int kk  = enc >> 20;
            bf16_t* orow = pairbuf + ((size_t)(tok * 2 + kk)) * NH;
            #pragma unroll
            for (int nt = 0; nt < 4; nt++) {
                int col = wave * 64 + nt * 16 + q * 4;
                bf16x4 ov;
                #pragma unroll
                for (int r = 0; r < 4; r++)
                    ov[r] = (bf16_t)((oacc[mt][nt][r] + ((const float*)&b2v[nt])[r]) * gw);
                if (valid) *(bf16x4*)&orow[col] = ov;
            }
        }
    }
}

// ---------------------------------------------------------------------------
// Kernel 3: residual + LayerNorm, vectorized. Wave-per-token (64 lanes x 4 h),
// float4/bf16x4 loads, shfl_xor reduce, no LDS, no syncthreads.
// ---------------------------------------------------------------------------
__global__ __launch_bounds__(256) void ln_kernel(
    const float* __restrict__ x, const bf16_t* __restrict__ pairbuf,
    const float* __restrict__ gamma, const float* __restrict__ beta,
    float* __restrict__ out)
{
    int tok  = blockIdx.x * 4 + (threadIdx.x >> 6);
    int lane = threadIdx.x & 63;
    float4 xv = *(const float4*)(x + (size_t)tok * NH + lane * 4);
    bf16x4 p0 = *(const bf16x4*)(pairbuf + (size_t)(tok * 2)     * NH + lane * 4);
    bf16x4 p1 = *(const bf16x4*)(pairbuf + (size_t)(tok * 2 + 1) * NH + lane * 4);
    float y0 = xv.x + (float)p0[0] + (float)p1[0];
    float y1 = xv.y + (float)p0[1] + (float)p1[1];
    float y2 = xv.z + (float)p0[2] + (float)p1[2];
    float y3 = xv.w + (float)p0[3] + (float)p1[3];
    float s  = y0 + y1 + y2 + y3;
    float s2 = y0 * y0 + y1 * y1 + y2 * y2 + y3 * y3;
    #pragma unroll
    for (int o = 32; o > 0; o >>= 1) {
        s  += __shfl_xor(s, o);
        s2 += __shfl_xor(s2, o);
    }
    float mu   = s * (1.f / NH);
    float var  = s2 * (1.f / NH) - mu * mu;
    float rstd = rsqrtf(var + 1e-5f);
    float4 gv = *(const float4*)(gamma + lane * 4);
    float4 bv = *(const float4*)(beta  + lane * 4);
    float4 o4;
    o4.x = (y0 - mu) * rstd * gv.x + bv.x;
    o4.y = (y1 - mu) * rstd * gv.y + bv.y;
    o4.z = (y2 - mu) * rstd * gv.z + bv.z;
    o4.w = (y3 - mu) * rstd * gv.w + bv.w;
    *(float4*)(out + (size_t)tok * NH + lane * 4) = o4;
}

// ---------------------------------------------------------------------------
extern "C" void kernel_launch(void* const* d_in, const int* in_sizes, int n_in,
                              void* d_out, int out_size, void* d_ws, size_t ws_size,
                              hipStream_t stream) {
    const float* x      = (const float*)d_in[0];
    const float* gate_w = (const float*)d_in[1];
    const float* gate_b = (const float*)d_in[2];
    const float* w1     = (const float*)d_in[3];
    const float* b1     = (const float*)d_in[4];
    const float* w2     = (const float*)d_in[5];
    const float* b2     = (const float*)d_in[6];
    const float* gamma  = (const float*)d_in[7];
    const float* beta   = (const float*)d_in[8];
    float* out = (float*)d_out;

    char* ws = (char*)d_ws;
    const size_t MB = 1024 * 1024;
    int*    counts     = (int*)ws;                       // 256 B
    int*    bucket_enc = (int*)(ws + 256);               // 2 MB
    float*  bucket_gw  = (float*)(ws + 256 + 2 * MB);    // 2 MB
    bf16_t* w1t        = (bf16_t*)(ws + 256 + 4 * MB);   // 4 MB
    bf16_t* w2t        = (bf16_t*)(ws + 256 + 8 * MB);   // 4 MB
    bf16_t* xb         = (bf16_t*)(ws + 256 + 12 * MB);  // 16 MB
    bf16_t* pairbuf    = (bf16_t*)(ws + 256 + 28 * MB);  // 32 MB

    hipMemsetAsync(counts, 0, 256, stream);
    prep_kernel<<<4224, 256, 0, stream>>>(w1, w2, w1t, w2t,
                                          x, gate_w, gate_b,
                                          counts, bucket_enc, bucket_gw, xb);
    moe_kernel<<<768, 256, 0, stream>>>(xb, w1t, b1, w2t, b2, counts, bucket_enc, bucket_gw, pairbuf);
    ln_kernel<<<NTOK / 4, 256, 0, stream>>>(x, pairbuf, gamma, beta, out);
}